// Round 1
// baseline (857.890 us; speedup 1.0000x reference)
//
#include <hip/hip_runtime.h>
#include <hip/hip_bf16.h>

// Geometry (fixed): B=1, C=8, D=H=W=128.
constexpr int HW2 = 16384;
constexpr int DHW = 2097152;

// MFMA staging: LDS cell = 8 ci (bf16, 16 B) at (g = dz*3+dy group, xi).
// Pitch 13 groups (208 B): b128 lane-stride 52 words -> 8 lanes tile all 32
// banks exactly once => conflict-free staging writes AND fragment reads.
constexpr int PKG = 13;   // groups per xi row (9 used + 3 K-pad + 1 pitch pad)
constexpr int XT  = 130;  // staged x extent: x = -1 .. 128

typedef short bf16x8 __attribute__((ext_vector_type(8)));  // 8 bf16 = 4 VGPR
typedef float f32x4  __attribute__((ext_vector_type(4)));

__device__ inline unsigned short f2b(float f) {
  __hip_bfloat16 h = __float2bfloat16(f);
  return *(unsigned short*)&h;
}
__device__ inline float b2f(unsigned short u) {
  __hip_bfloat16 h = *(__hip_bfloat16*)&u;
  return __bfloat162float(h);
}

// ---------------------------------------------------------------------------
// Prep: pack w1/w2 into MFMA A-fragment order, bf16, dx-split.
//   k = s*32 + q*8 + j  ->  g = s*4+q (= (dz)*3+(dy), <9 valid), ci = j.
//   Wpack2: [(dx*3+s)*2+Mt][lane][j], oc = Mt*16+(lane&15) (<27)
//   Wpack1: [dx*3+s][lane][j],        oc = lane&15 (<8)
// ---------------------------------------------------------------------------
__global__ __launch_bounds__(256) void k_prep(
    const float* __restrict__ w1, const float* __restrict__ w2,
    unsigned short* __restrict__ Wpack2, unsigned short* __restrict__ Wpack1) {
  int i = blockIdx.x * 256 + threadIdx.x;
  if (i < 9216) {
    int j = i & 7;
    int lane = (i >> 3) & 63;
    int Mt = (i >> 9) & 1;
    int g2 = i >> 10;         // dx*3 + s
    int s = g2 % 3, dx = g2 / 3;
    int oc = Mt * 16 + (lane & 15);
    int kr = s * 32 + (lane >> 4) * 8 + j;
    int ci = kr & 7, g = kr >> 3;
    float w = 0.f;
    if (oc < 27 && g < 9) {
      int dzr = g / 3, dyr = g % 3;
      w = w2[(oc * 8 + ci) * 27 + dzr * 9 + dyr * 3 + dx];
    }
    Wpack2[i] = f2b(w);
  }
  int jj = i - 9216;
  if (jj >= 0 && jj < 4608) {
    int j = jj & 7;
    int lane = (jj >> 3) & 63;
    int g2 = jj >> 9;         // dx*3 + s
    int s = g2 % 3, dx = g2 / 3;
    int oc = lane & 15;
    int kr = s * 32 + (lane >> 4) * 8 + j;
    int ci = kr & 7, g = kr >> 3;
    float w = 0.f;
    if (oc < 8 && g < 9) {
      int dzr = g / 3, dyr = g % 3;
      w = w1[(oc * 8 + ci) * 27 + dzr * 9 + dyr * 3 + dx];
    }
    Wpack1[jj] = f2b(w);
  }
}

// ---------------------------------------------------------------------------
// Transpose x: [ci][z][y][x] fp32 -> [z][y][x][ci] bf16 (xb, for conv1 MFMA)
//                                 and [z][y][x][ci] fp32 (xi, for adapt pass)
// ---------------------------------------------------------------------------
__global__ __launch_bounds__(256) void k_xpose(
    const float* __restrict__ x, unsigned short* __restrict__ xb,
    float* __restrict__ xi) {
  int idx = blockIdx.x * 256 + threadIdx.x;  // voxel
  float f[8];
  unsigned v[4];
#pragma unroll
  for (int p = 0; p < 4; ++p) {
    f[2 * p]     = x[(size_t)(2 * p) * DHW + idx];
    f[2 * p + 1] = x[(size_t)(2 * p + 1) * DHW + idx];
    unsigned lo = f2b(f[2 * p]);
    unsigned hi = f2b(f[2 * p + 1]);
    v[p] = lo | (hi << 16);
  }
  ((uint4*)xb)[idx] = make_uint4(v[0], v[1], v[2], v[3]);
  float4* xo = (float4*)(xi + (size_t)idx * 8);
  xo[0] = make_float4(f[0], f[1], f[2], f[3]);
  xo[1] = make_float4(f[4], f[5], f[6], f[7]);
}

// ---------------------------------------------------------------------------
// Kernel 1: conv3d(x, w1) + bias + ReLU (8 -> 8), implicit-GEMM MFMA.
// ---------------------------------------------------------------------------
__global__ __launch_bounds__(256) void k_conv1m(
    const unsigned short* __restrict__ xb,
    const unsigned short* __restrict__ Wpack1,
    const float* __restrict__ b1, unsigned short* __restrict__ hb) {
  __shared__ __align__(16) unsigned short T[XT * PKG * 8];
  const int tid  = threadIdx.x;
  const int lane = tid & 63;
  const int wv   = tid >> 6;
  const int z0 = blockIdx.x >> 7;
  const int y0 = blockIdx.x & 127;

  bf16x8 wf[3][3];
  {
    const bf16x8* wp = (const bf16x8*)Wpack1;
#pragma unroll
    for (int dx = 0; dx < 3; ++dx)
#pragma unroll
      for (int s = 0; s < 3; ++s)
        wf[dx][s] = wp[(dx * 3 + s) * 64 + lane];
  }

  const uint4* src = (const uint4*)xb;
  uint4* dst = (uint4*)T;
#pragma unroll 1
  for (int c = tid; c < 12 * XT; c += 256) {
    int g  = c / XT;          // 0..11
    int xi = c - g * XT;
    uint4 v = make_uint4(0u, 0u, 0u, 0u);
    if (g < 9) {
      int z = z0 + g / 3 - 1, y = y0 + g % 3 - 1, xg = xi - 1;
      if ((unsigned)z < 128u && (unsigned)y < 128u && (unsigned)xg < 128u)
        v = src[(z * 128 + y) * 128 + xg];
    }
    dst[xi * PKG + g] = v;
  }
  __syncthreads();

  f32x4 acc[2];
#pragma unroll
  for (int nt = 0; nt < 2; ++nt) acc[nt] = (f32x4){0.f, 0.f, 0.f, 0.f};

  const int n = lane & 15;
  const int q = lane >> 4;
  const int xbase = wv * 32 + n;

#pragma unroll
  for (int dx = 0; dx < 3; ++dx) {
#pragma unroll
    for (int s = 0; s < 3; ++s) {
      bf16x8 bfr[2];
#pragma unroll
      for (int nt = 0; nt < 2; ++nt) {
        int off = ((xbase + nt * 16 + dx) * PKG + (s * 4 + q)) * 8;
        bfr[nt] = *(const bf16x8*)&T[off];
      }
#pragma unroll
      for (int nt = 0; nt < 2; ++nt)
        acc[nt] = __builtin_amdgcn_mfma_f32_16x16x32_bf16(
            wf[dx][s], bfr[nt], acc[nt], 0, 0, 0);
    }
  }

  // Epilogue: +bias, ReLU -> hb[vox*8 + oc] (ushort4 per lane-half)
  const int voxrow = (z0 * 128 + y0) * 128;
  if (q < 2) {
#pragma unroll
    for (int nt = 0; nt < 2; ++nt) {
      const int vox = voxrow + wv * 32 + nt * 16 + n;
      ushort4 o;
      o.x = f2b(fmaxf(acc[nt][0] + b1[q * 4 + 0], 0.f));
      o.y = f2b(fmaxf(acc[nt][1] + b1[q * 4 + 1], 0.f));
      o.z = f2b(fmaxf(acc[nt][2] + b1[q * 4 + 2], 0.f));
      o.w = f2b(fmaxf(acc[nt][3] + b1[q * 4 + 3], 0.f));
      *(ushort4*)(hb + (size_t)vox * 8 + q * 4) = o;
    }
  }
}

// ---------------------------------------------------------------------------
// Kernel 2: conv3d(h, w2) (8 -> 27) + fused L1 norm, implicit-GEMM MFMA.
// ---------------------------------------------------------------------------
__global__ __launch_bounds__(256) void k_conv2(
    const unsigned short* __restrict__ hb,
    const unsigned short* __restrict__ Wpack2,
    unsigned short* __restrict__ wn) {
  __shared__ __align__(16) unsigned short T[XT * PKG * 8];
  const int tid  = threadIdx.x;
  const int lane = tid & 63;
  const int wv   = tid >> 6;
  const int z0 = blockIdx.x >> 7;
  const int y0 = blockIdx.x & 127;

  bf16x8 wf[3][3][2];
  {
    const bf16x8* wp = (const bf16x8*)Wpack2;
#pragma unroll
    for (int dx = 0; dx < 3; ++dx)
#pragma unroll
      for (int s = 0; s < 3; ++s)
#pragma unroll
        for (int mt = 0; mt < 2; ++mt)
          wf[dx][s][mt] = wp[((dx * 3 + s) * 2 + mt) * 64 + lane];
  }

  const uint4* src = (const uint4*)hb;
  uint4* dst = (uint4*)T;
#pragma unroll 1
  for (int c = tid; c < 12 * XT; c += 256) {
    int g  = c / XT;
    int xi = c - g * XT;
    uint4 v = make_uint4(0u, 0u, 0u, 0u);
    if (g < 9) {
      int z = z0 + g / 3 - 1, y = y0 + g % 3 - 1, xg = xi - 1;
      if ((unsigned)z < 128u && (unsigned)y < 128u && (unsigned)xg < 128u)
        v = src[(z * 128 + y) * 128 + xg];
    }
    dst[xi * PKG + g] = v;
  }
  __syncthreads();

  f32x4 acc[2][2];  // [nt][mt]
#pragma unroll
  for (int nt = 0; nt < 2; ++nt)
#pragma unroll
    for (int mt = 0; mt < 2; ++mt) acc[nt][mt] = (f32x4){0.f, 0.f, 0.f, 0.f};

  const int n = lane & 15;
  const int q = lane >> 4;
  const int xbase = wv * 32 + n;

#pragma unroll
  for (int dx = 0; dx < 3; ++dx) {
#pragma unroll
    for (int s = 0; s < 3; ++s) {
      bf16x8 bfr[2];
#pragma unroll
      for (int nt = 0; nt < 2; ++nt) {
        int off = ((xbase + nt * 16 + dx) * PKG + (s * 4 + q)) * 8;
        bfr[nt] = *(const bf16x8*)&T[off];
      }
#pragma unroll
      for (int mt = 0; mt < 2; ++mt)
#pragma unroll
        for (int nt = 0; nt < 2; ++nt)
          acc[nt][mt] = __builtin_amdgcn_mfma_f32_16x16x32_bf16(
              wf[dx][s][mt], bfr[nt], acc[nt][mt], 0, 0, 0);
    }
  }

  const int voxrow = (z0 * 128 + y0) * 128;
#pragma unroll
  for (int nt = 0; nt < 2; ++nt) {
    float ns = 0.f;
#pragma unroll
    for (int r = 0; r < 4; ++r) ns += fabsf(acc[nt][0][r]);
#pragma unroll
    for (int r = 0; r < 4; ++r) {
      int oc = 16 + q * 4 + r;
      ns += (oc < 27) ? fabsf(acc[nt][1][r]) : 0.f;
    }
    ns += __shfl_xor(ns, 16);
    ns += __shfl_xor(ns, 32);
    float sc = 1.f / fmaxf(ns, 1e-12f);
    const int vox = voxrow + wv * 32 + nt * 16 + n;
#pragma unroll
    for (int r = 0; r < 4; ++r) {
      int oc = q * 4 + r;
      wn[(size_t)oc * DHW + vox] = f2b(acc[nt][0][r] * sc);
    }
#pragma unroll
    for (int r = 0; r < 4; ++r) {
      int oc = 16 + q * 4 + r;
      if (oc < 27)
        wn[(size_t)oc * DHW + vox] = f2b(acc[nt][1][r] * sc);
    }
  }
}

// ---------------------------------------------------------------------------
// Kernel 3: adaptive 3x3x3 conv on channel-interleaved fp32 activations.
// in:  [vox][c=8] fp32 (32 B/voxel). wn: [tap=27][vox] bf16 (planar).
// out: interleaved (FINAL=0) or planar [c][vox] fp32 (FINAL=1).
// 4 voxels (x0..x0+3) per thread. Branch-free: invalid (dz,dy) rows are
// address-clamped and their WEIGHTS zeroed; x-edge positions zeroed in data.
// Per group: 3 ushort4 weight loads + 12 dense float4 loads from ONE stream
// (vs 24 loads across 8 planar streams before) -> deep load pipelining.
// ---------------------------------------------------------------------------
template <int FINAL>
__global__ __launch_bounds__(256) void k_adapt_i(
    const float* __restrict__ in, const unsigned short* __restrict__ wn,
    float* __restrict__ out) {
  const int t = blockIdx.x * 256 + threadIdx.x;  // [0, DHW/4)
  const int xg = (t & 31) * 4;
  const int rest = t >> 5;        // z*128 + y
  const int y = rest & 127;
  const int z = rest >> 7;
  const int vox0 = rest * 128 + xg;

  float acc[8][4];
#pragma unroll
  for (int c = 0; c < 8; ++c)
#pragma unroll
    for (int v = 0; v < 4; ++v) acc[c][v] = 0.f;

#pragma unroll
  for (int g = 0; g < 9; ++g) {
    const int dz = g / 3 - 1, dy = g % 3 - 1;
    const int zz = z + dz, yy = y + dy;
    const bool valid = ((unsigned)zz < 128u) && ((unsigned)yy < 128u);
    const int rowi = valid ? (zz * 128 + yy) : rest;  // safe fallback row
    const float* __restrict__ rowp = in + (size_t)rowi * (128 * 8);

    // Per-voxel weights for the 3 x-taps of this (dz,dy); zeroed if invalid.
    float wt[3][4];
#pragma unroll
    for (int dxi = 0; dxi < 3; ++dxi) {
      ushort4 wv4 = *(const ushort4*)(wn + (size_t)(g * 3 + dxi) * DHW + vox0);
      wt[dxi][0] = valid ? b2f(wv4.x) : 0.f;
      wt[dxi][1] = valid ? b2f(wv4.y) : 0.f;
      wt[dxi][2] = valid ? b2f(wv4.z) : 0.f;
      wt[dxi][3] = valid ? b2f(wv4.w) : 0.f;
    }

    // Stream 6 interleaved positions x = xg-1 .. xg+4 (8 ch each).
#pragma unroll
    for (int p = 0; p < 6; ++p) {
      int xm = xg - 1 + p;
      if (p == 0) xm = (xg == 0) ? 0 : xm;        // clamp; data zeroed below
      if (p == 5) xm = (xg == 124) ? 127 : xm;
      const float4* pp = (const float4*)(rowp + (size_t)xm * 8);
      float4 xa = pp[0];
      float4 xbv = pp[1];
      if (p == 0 && xg == 0) {
        xa = make_float4(0.f, 0.f, 0.f, 0.f);
        xbv = make_float4(0.f, 0.f, 0.f, 0.f);
      }
      if (p == 5 && xg == 124) {
        xa = make_float4(0.f, 0.f, 0.f, 0.f);
        xbv = make_float4(0.f, 0.f, 0.f, 0.f);
      }
      float xc[8] = {xa.x, xa.y, xa.z, xa.w, xbv.x, xbv.y, xbv.z, xbv.w};
      // output voxel v uses position p = v + dxi
#pragma unroll
      for (int dxi = 0; dxi < 3; ++dxi) {
        const int v = p - dxi;
        if (v >= 0 && v < 4) {
          const float w = wt[dxi][v];
#pragma unroll
          for (int c = 0; c < 8; ++c)
            acc[c][v] = fmaf(xc[c], w, acc[c][v]);
        }
      }
    }
  }

  if (FINAL) {
    // planar fp32 [c][vox]
#pragma unroll
    for (int c = 0; c < 8; ++c) {
      float4 o = make_float4(acc[c][0], acc[c][1], acc[c][2], acc[c][3]);
      *(float4*)(out + (size_t)c * DHW + vox0) = o;
    }
  } else {
    // interleaved fp32 [vox][c]
#pragma unroll
    for (int v = 0; v < 4; ++v) {
      float4 lo = make_float4(acc[0][v], acc[1][v], acc[2][v], acc[3][v]);
      float4 hi = make_float4(acc[4][v], acc[5][v], acc[6][v], acc[7][v]);
      float4* op = (float4*)(out + (size_t)(vox0 + v) * 8);
      op[0] = lo;
      op[1] = hi;
    }
  }
}

// ---------------------------------------------------------------------------
extern "C" void kernel_launch(void* const* d_in, const int* in_sizes, int n_in,
                              void* d_out, int out_size, void* d_ws, size_t ws_size,
                              hipStream_t stream) {
  const float* x  = (const float*)d_in[0];
  const float* w1 = (const float*)d_in[1];
  const float* b1 = (const float*)d_in[2];
  const float* w2 = (const float*)d_in[3];
  float* out = (float*)d_out;

  // Workspace layout (236 MiB + packs, same footprint as before):
  //   [0,   32M): xb bf16 interleaved   \__ reused as ti (64 MiB fp32
  //   [32M, 64M): hb bf16 interleaved   /   interleaved) during adapt
  //   [64M, 172M): wn bf16 planar (27 x DHW)
  //   [172M, 236M): xi fp32 interleaved
  //   [236M, ...): Wpack2, Wpack1
  char* ws = (char*)d_ws;
  unsigned short* xb = (unsigned short*)ws;
  unsigned short* hb = (unsigned short*)(ws + (size_t)8 * DHW * 2);
  float* ti = (float*)ws;  // aliases xb+hb (both dead before adapt)
  unsigned short* wn = (unsigned short*)(ws + (size_t)16 * DHW * 2);
  float* xi = (float*)(ws + (size_t)16 * DHW * 2 + (size_t)27 * DHW * 2);
  unsigned short* Wpack2 =
      (unsigned short*)(ws + (size_t)16 * DHW * 2 + (size_t)27 * DHW * 2 +
                        (size_t)8 * DHW * 4);
  unsigned short* Wpack1 = Wpack2 + 9216;

  dim3 blk(256);
  k_prep<<<54, blk, 0, stream>>>(w1, w2, Wpack2, Wpack1);
  k_xpose<<<DHW / 256, blk, 0, stream>>>(x, xb, xi);
  k_conv1m<<<128 * 128, blk, 0, stream>>>(xb, Wpack1, b1, hb);
  k_conv2<<<128 * 128, blk, 0, stream>>>(hb, Wpack2, wn);
  // adaptive ping-pong on interleaved fp32: xi -> ti -> xi -> out (planar)
  k_adapt_i<0><<<DHW / 4 / 256, blk, 0, stream>>>(xi, wn, ti);
  k_adapt_i<0><<<DHW / 4 / 256, blk, 0, stream>>>(ti, wn, xi);
  k_adapt_i<1><<<DHW / 4 / 256, blk, 0, stream>>>(xi, wn, out);
}

// Round 3
// 624.002 us; speedup vs baseline: 1.3748x; 1.3748x over previous
//
#include <hip/hip_runtime.h>
#include <hip/hip_bf16.h>

// Geometry (fixed): B=1, C=8, D=H=W=128.
constexpr int HW2 = 16384;
constexpr int DHW = 2097152;

// MFMA staging: LDS cell = 8 ci (bf16, 16 B) at (g = dz*3+dy group, xi).
constexpr int PKG = 13;   // groups per xi row (9 used + 3 K-pad + 1 pitch pad)
constexpr int XT  = 130;  // staged x extent: x = -1 .. 128

typedef short bf16x8 __attribute__((ext_vector_type(8)));  // 8 bf16 = 4 VGPR
typedef float f32x4  __attribute__((ext_vector_type(4)));

__device__ inline unsigned short f2b(float f) {
  __hip_bfloat16 h = __float2bfloat16(f);
  return *(unsigned short*)&h;
}
__device__ inline float b2f(unsigned short u) {
  __hip_bfloat16 h = *(__hip_bfloat16*)&u;
  return __bfloat162float(h);
}

// ---------------------------------------------------------------------------
// Prep: pack w1/w2 into MFMA A-fragment order, bf16, dx-split.
// Extra block (54) zero-fills the 32-B x-window guard regions around ti/xi
// so edge-tap garbage reads are finite (their weights are zeroed in k_adapt2).
// ---------------------------------------------------------------------------
__global__ __launch_bounds__(256) void k_prep(
    const float* __restrict__ w1, const float* __restrict__ w2,
    unsigned short* __restrict__ Wpack2, unsigned short* __restrict__ Wpack1,
    float* __restrict__ g_ti, float* __restrict__ g_xi) {
  int i = blockIdx.x * 256 + threadIdx.x;
  if (i < 9216) {
    int j = i & 7;
    int lane = (i >> 3) & 63;
    int Mt = (i >> 9) & 1;
    int g2 = i >> 10;         // dx*3 + s
    int s = g2 % 3, dx = g2 / 3;
    int oc = Mt * 16 + (lane & 15);
    int kr = s * 32 + (lane >> 4) * 8 + j;
    int ci = kr & 7, g = kr >> 3;
    float w = 0.f;
    if (oc < 27 && g < 9) {
      int dzr = g / 3, dyr = g % 3;
      w = w2[(oc * 8 + ci) * 27 + dzr * 9 + dyr * 3 + dx];
    }
    Wpack2[i] = f2b(w);
  }
  int jj = i - 9216;
  if (jj >= 0 && jj < 4608) {
    int j = jj & 7;
    int lane = (jj >> 3) & 63;
    int g2 = jj >> 9;         // dx*3 + s
    int s = g2 % 3, dx = g2 / 3;
    int oc = lane & 15;
    int kr = s * 32 + (lane >> 4) * 8 + j;
    int ci = kr & 7, g = kr >> 3;
    float w = 0.f;
    if (oc < 8 && g < 9) {
      int dzr = g / 3, dyr = g % 3;
      w = w1[(oc * 8 + ci) * 27 + dzr * 9 + dyr * 3 + dx];
    }
    Wpack1[jj] = f2b(w);
  }
  int gg = i - 13824;
  if (gg >= 0 && gg < 32) {
    float* p = (gg < 8)  ? (g_ti - 8 + gg)
             : (gg < 16) ? (g_ti + (size_t)8 * DHW + (gg - 8))
             : (gg < 24) ? (g_xi - 8 + (gg - 16))
                         : (g_xi + (size_t)8 * DHW + (gg - 24));
    *p = 0.f;
  }
}

// ---------------------------------------------------------------------------
// Transpose x: [ci][z][y][x] fp32 -> [z][y][x][ci] bf16 (xb, for conv1 MFMA)
//                                 and [z][y][x][ci] fp32 (xi, for adapt pass)
// ---------------------------------------------------------------------------
__global__ __launch_bounds__(256) void k_xpose(
    const float* __restrict__ x, unsigned short* __restrict__ xb,
    float* __restrict__ xi) {
  int idx = blockIdx.x * 256 + threadIdx.x;  // voxel
  float f[8];
  unsigned v[4];
#pragma unroll
  for (int p = 0; p < 4; ++p) {
    f[2 * p]     = x[(size_t)(2 * p) * DHW + idx];
    f[2 * p + 1] = x[(size_t)(2 * p + 1) * DHW + idx];
    unsigned lo = f2b(f[2 * p]);
    unsigned hi = f2b(f[2 * p + 1]);
    v[p] = lo | (hi << 16);
  }
  ((uint4*)xb)[idx] = make_uint4(v[0], v[1], v[2], v[3]);
  float4* xo = (float4*)(xi + (size_t)idx * 8);
  xo[0] = make_float4(f[0], f[1], f[2], f[3]);
  xo[1] = make_float4(f[4], f[5], f[6], f[7]);
}

// ---------------------------------------------------------------------------
// Kernel 1: conv3d(x, w1) + bias + ReLU (8 -> 8), implicit-GEMM MFMA.
// ---------------------------------------------------------------------------
__global__ __launch_bounds__(256) void k_conv1m(
    const unsigned short* __restrict__ xb,
    const unsigned short* __restrict__ Wpack1,
    const float* __restrict__ b1, unsigned short* __restrict__ hb) {
  __shared__ __align__(16) unsigned short T[XT * PKG * 8];
  const int tid  = threadIdx.x;
  const int lane = tid & 63;
  const int wv   = tid >> 6;
  const int z0 = blockIdx.x >> 7;
  const int y0 = blockIdx.x & 127;

  bf16x8 wf[3][3];
  {
    const bf16x8* wp = (const bf16x8*)Wpack1;
#pragma unroll
    for (int dx = 0; dx < 3; ++dx)
#pragma unroll
      for (int s = 0; s < 3; ++s)
        wf[dx][s] = wp[(dx * 3 + s) * 64 + lane];
  }

  const uint4* src = (const uint4*)xb;
  uint4* dst = (uint4*)T;
#pragma unroll 1
  for (int c = tid; c < 12 * XT; c += 256) {
    int g  = c / XT;          // 0..11
    int xi = c - g * XT;
    uint4 v = make_uint4(0u, 0u, 0u, 0u);
    if (g < 9) {
      int z = z0 + g / 3 - 1, y = y0 + g % 3 - 1, xg = xi - 1;
      if ((unsigned)z < 128u && (unsigned)y < 128u && (unsigned)xg < 128u)
        v = src[(z * 128 + y) * 128 + xg];
    }
    dst[xi * PKG + g] = v;
  }
  __syncthreads();

  f32x4 acc[2];
#pragma unroll
  for (int nt = 0; nt < 2; ++nt) acc[nt] = (f32x4){0.f, 0.f, 0.f, 0.f};

  const int n = lane & 15;
  const int q = lane >> 4;
  const int xbase = wv * 32 + n;

#pragma unroll
  for (int dx = 0; dx < 3; ++dx) {
#pragma unroll
    for (int s = 0; s < 3; ++s) {
      bf16x8 bfr[2];
#pragma unroll
      for (int nt = 0; nt < 2; ++nt) {
        int off = ((xbase + nt * 16 + dx) * PKG + (s * 4 + q)) * 8;
        bfr[nt] = *(const bf16x8*)&T[off];
      }
#pragma unroll
      for (int nt = 0; nt < 2; ++nt)
        acc[nt] = __builtin_amdgcn_mfma_f32_16x16x32_bf16(
            wf[dx][s], bfr[nt], acc[nt], 0, 0, 0);
    }
  }

  const int voxrow = (z0 * 128 + y0) * 128;
  if (q < 2) {
#pragma unroll
    for (int nt = 0; nt < 2; ++nt) {
      const int vox = voxrow + wv * 32 + nt * 16 + n;
      ushort4 o;
      o.x = f2b(fmaxf(acc[nt][0] + b1[q * 4 + 0], 0.f));
      o.y = f2b(fmaxf(acc[nt][1] + b1[q * 4 + 1], 0.f));
      o.z = f2b(fmaxf(acc[nt][2] + b1[q * 4 + 2], 0.f));
      o.w = f2b(fmaxf(acc[nt][3] + b1[q * 4 + 3], 0.f));
      *(ushort4*)(hb + (size_t)vox * 8 + q * 4) = o;
    }
  }
}

// ---------------------------------------------------------------------------
// Kernel 2: conv3d(h, w2) (8 -> 27) + fused L1 norm, implicit-GEMM MFMA.
// ---------------------------------------------------------------------------
__global__ __launch_bounds__(256) void k_conv2(
    const unsigned short* __restrict__ hb,
    const unsigned short* __restrict__ Wpack2,
    unsigned short* __restrict__ wn) {
  __shared__ __align__(16) unsigned short T[XT * PKG * 8];
  const int tid  = threadIdx.x;
  const int lane = tid & 63;
  const int wv   = tid >> 6;
  const int z0 = blockIdx.x >> 7;
  const int y0 = blockIdx.x & 127;

  bf16x8 wf[3][3][2];
  {
    const bf16x8* wp = (const bf16x8*)Wpack2;
#pragma unroll
    for (int dx = 0; dx < 3; ++dx)
#pragma unroll
      for (int s = 0; s < 3; ++s)
#pragma unroll
        for (int mt = 0; mt < 2; ++mt)
          wf[dx][s][mt] = wp[((dx * 3 + s) * 2 + mt) * 64 + lane];
  }

  const uint4* src = (const uint4*)hb;
  uint4* dst = (uint4*)T;
#pragma unroll 1
  for (int c = tid; c < 12 * XT; c += 256) {
    int g  = c / XT;
    int xi = c - g * XT;
    uint4 v = make_uint4(0u, 0u, 0u, 0u);
    if (g < 9) {
      int z = z0 + g / 3 - 1, y = y0 + g % 3 - 1, xg = xi - 1;
      if ((unsigned)z < 128u && (unsigned)y < 128u && (unsigned)xg < 128u)
        v = src[(z * 128 + y) * 128 + xg];
    }
    dst[xi * PKG + g] = v;
  }
  __syncthreads();

  f32x4 acc[2][2];  // [nt][mt]
#pragma unroll
  for (int nt = 0; nt < 2; ++nt)
#pragma unroll
    for (int mt = 0; mt < 2; ++mt) acc[nt][mt] = (f32x4){0.f, 0.f, 0.f, 0.f};

  const int n = lane & 15;
  const int q = lane >> 4;
  const int xbase = wv * 32 + n;

#pragma unroll
  for (int dx = 0; dx < 3; ++dx) {
#pragma unroll
    for (int s = 0; s < 3; ++s) {
      bf16x8 bfr[2];
#pragma unroll
      for (int nt = 0; nt < 2; ++nt) {
        int off = ((xbase + nt * 16 + dx) * PKG + (s * 4 + q)) * 8;
        bfr[nt] = *(const bf16x8*)&T[off];
      }
#pragma unroll
      for (int mt = 0; mt < 2; ++mt)
#pragma unroll
        for (int nt = 0; nt < 2; ++nt)
          acc[nt][mt] = __builtin_amdgcn_mfma_f32_16x16x32_bf16(
              wf[dx][s][mt], bfr[nt], acc[nt][mt], 0, 0, 0);
    }
  }

  const int voxrow = (z0 * 128 + y0) * 128;
#pragma unroll
  for (int nt = 0; nt < 2; ++nt) {
    float ns = 0.f;
#pragma unroll
    for (int r = 0; r < 4; ++r) ns += fabsf(acc[nt][0][r]);
#pragma unroll
    for (int r = 0; r < 4; ++r) {
      int oc = 16 + q * 4 + r;
      ns += (oc < 27) ? fabsf(acc[nt][1][r]) : 0.f;
    }
    ns += __shfl_xor(ns, 16);
    ns += __shfl_xor(ns, 32);
    float sc = 1.f / fmaxf(ns, 1e-12f);
    const int vox = voxrow + wv * 32 + nt * 16 + n;
#pragma unroll
    for (int r = 0; r < 4; ++r) {
      int oc = q * 4 + r;
      wn[(size_t)oc * DHW + vox] = f2b(acc[nt][0][r] * sc);
    }
#pragma unroll
    for (int r = 0; r < 4; ++r) {
      int oc = 16 + q * 4 + r;
      if (oc < 27)
        wn[(size_t)oc * DHW + vox] = f2b(acc[nt][1][r] * sc);
    }
  }
}

// ---------------------------------------------------------------------------
// Kernel 3: adaptive 3x3x3 conv, interleaved fp32 in [vox][8]; planar bf16 wn.
// Thread = 4 consecutive x voxels. Steady-state g-loop (unroll 1) keeps the
// live set ~112 VGPR; __launch_bounds__(256,4) caps at 128 -> 16 waves/CU.
// Branch-free: invalid (dz,dy) rows address-clamped, their weights zeroed;
// x-edge taps weight-zeroed (guard regions zero-filled by k_prep so the
// dead loads are finite). Middle passes: 16-KiB two-phase LDS transpose so
// every global store is 1 KiB lane-contiguous (fixes R1's 2.3x write amp).
// ---------------------------------------------------------------------------
template <int FINAL>
__global__ __launch_bounds__(256, 4) void k_adapt2(
    const float* __restrict__ in, const unsigned short* __restrict__ wn,
    float* __restrict__ out) {
  __shared__ __align__(16) float S[4096];  // 16 KiB
  const int tid = threadIdx.x;
  const int t = blockIdx.x * 256 + tid;
  const int xg = (t & 31) * 4;
  const int rest = t >> 5;        // z*128 + y
  const int y = rest & 127;
  const int z = rest >> 7;
  const int vox0 = rest * 128 + xg;

  f32x4 accA[4], accB[4];  // accA[v] = ch 0..3, accB[v] = ch 4..7
#pragma unroll
  for (int v = 0; v < 4; ++v) {
    accA[v] = (f32x4){0.f, 0.f, 0.f, 0.f};
    accB[v] = (f32x4){0.f, 0.f, 0.f, 0.f};
  }

  const float* inx = in + (size_t)xg * 8 - 8;      // x window base (x = xg-1)
  const unsigned short* wpg = wn + vox0;           // tap pointer, += 3*DHW/iter

#pragma unroll 1
  for (int g = 0; g < 9; ++g) {
    const int dz = g / 3 - 1, dy = g % 3 - 1;
    const int zz = z + dz, yy = y + dy;
    const bool valid = ((unsigned)zz < 128u) & ((unsigned)yy < 128u);
    const int rowi = valid ? (zz * 128 + yy) : rest;  // safe fallback row
    const float* rowb = inx + (size_t)rowi * 1024;

    // 12 b128 input loads, one stream, immediate offsets 0..191 B.
    f32x4 XA[6], XB[6];
#pragma unroll
    for (int p = 0; p < 6; ++p) {
      XA[p] = *(const f32x4*)(rowb + p * 8);
      XB[p] = *(const f32x4*)(rowb + p * 8 + 4);
    }

    // 3 ushort4 weight loads; zero-select handles row/edge validity.
    ushort4 w0 = *(const ushort4*)(wpg);
    ushort4 w1 = *(const ushort4*)(wpg + DHW);
    ushort4 w2 = *(const ushort4*)(wpg + 2 * DHW);
    wpg += 3 * DHW;

    float wt[3][4];
    wt[0][0] = valid ? b2f(w0.x) : 0.f;
    wt[0][1] = valid ? b2f(w0.y) : 0.f;
    wt[0][2] = valid ? b2f(w0.z) : 0.f;
    wt[0][3] = valid ? b2f(w0.w) : 0.f;
    wt[1][0] = valid ? b2f(w1.x) : 0.f;
    wt[1][1] = valid ? b2f(w1.y) : 0.f;
    wt[1][2] = valid ? b2f(w1.z) : 0.f;
    wt[1][3] = valid ? b2f(w1.w) : 0.f;
    wt[2][0] = valid ? b2f(w2.x) : 0.f;
    wt[2][1] = valid ? b2f(w2.y) : 0.f;
    wt[2][2] = valid ? b2f(w2.z) : 0.f;
    wt[2][3] = valid ? b2f(w2.w) : 0.f;
    wt[0][0] = (xg == 0) ? 0.f : wt[0][0];      // x=-1 tap
    wt[2][3] = (xg == 124) ? 0.f : wt[2][3];    // x=128 tap

#pragma unroll
    for (int dxi = 0; dxi < 3; ++dxi) {
#pragma unroll
      for (int v = 0; v < 4; ++v) {
        const int p = v + dxi;
        const float w = wt[dxi][v];
#pragma unroll
        for (int c = 0; c < 4; ++c) {
          accA[v][c] = fmaf(XA[p][c], w, accA[v][c]);
          accB[v][c] = fmaf(XB[p][c], w, accB[v][c]);
        }
      }
    }
  }

  if (FINAL) {
    // planar fp32 [c][vox] -> d_out
#pragma unroll
    for (int c = 0; c < 4; ++c) {
      f32x4 o = {accA[0][c], accA[1][c], accA[2][c], accA[3][c]};
      *(f32x4*)(out + (size_t)c * DHW + vox0) = o;
      f32x4 o2 = {accB[0][c], accB[1][c], accB[2][c], accB[3][c]};
      *(f32x4*)(out + (size_t)(c + 4) * DHW + vox0) = o2;
    }
  } else {
    // interleaved fp32 [vox][8] via two-phase LDS transpose.
    // Block owns 32 KiB contiguous at out + blockIdx*8192 floats.
    const int row = tid >> 5;   // 0..7 (local y-ish row)
    const int col = tid & 31;   // x-group
    const size_t base = (size_t)blockIdx.x * 8192;  // floats
#pragma unroll
    for (int h = 0; h < 2; ++h) {
      __syncthreads();
      if ((row >> 2) == h) {
        const int lo = (row & 3) * 4096 + col * 128;  // bytes in phase
#pragma unroll
        for (int k = 0; k < 8; ++k) {
          int off = lo + k * 16;
          int swz = off ^ (((off >> 7) & 7) << 4);
          f32x4 val = (k & 1) ? accB[k >> 1] : accA[k >> 1];
          *(f32x4*)((char*)S + swz) = val;
        }
      }
      __syncthreads();
#pragma unroll
      for (int k = 0; k < 4; ++k) {
        int off = k * 4096 + tid * 16;  // bytes in phase, lane-contiguous
        int swz = off ^ (((off >> 7) & 7) << 4);
        f32x4 v = *(const f32x4*)((char*)S + swz);
        *(f32x4*)(out + base + h * 4096 + (off >> 2)) = v;
      }
    }
  }
}

// ---------------------------------------------------------------------------
extern "C" void kernel_launch(void* const* d_in, const int* in_sizes, int n_in,
                              void* d_out, int out_size, void* d_ws, size_t ws_size,
                              hipStream_t stream) {
  const float* x  = (const float*)d_in[0];
  const float* w1 = (const float*)d_in[1];
  const float* b1 = (const float*)d_in[2];
  const float* w2 = (const float*)d_in[3];
  float* out = (float*)d_out;

  // Workspace (~236 MiB + pads):
  //   [0,   64M): xb(32M)+hb(32M) bf16; reused as ti = ws+256 (64M fp32)
  //   [64M+4K, 172M+4K): wn bf16 planar (27 x DHW)
  //   [172M+12K, 236M+12K): xi fp32 interleaved
  //   then Wpack2, Wpack1. 256-B/4-KiB pads double as x-window guards
  //   (zero-filled by k_prep block 54).
  char* ws = (char*)d_ws;
  unsigned short* xb = (unsigned short*)ws;
  unsigned short* hb = (unsigned short*)(ws + (size_t)8 * DHW * 2);
  float* ti = (float*)(ws + 256);  // aliases xb+hb (both dead before adapt)
  unsigned short* wn = (unsigned short*)(ws + (size_t)16 * DHW * 2 + 4096);
  float* xi = (float*)(ws + (size_t)16 * DHW * 2 + 4096 +
                       (size_t)27 * DHW * 2 + 8192);
  unsigned short* Wpack2 =
      (unsigned short*)((char*)xi + (size_t)8 * DHW * 4 + 16384);
  unsigned short* Wpack1 = Wpack2 + 9216;

  dim3 blk(256);
  k_prep<<<55, blk, 0, stream>>>(w1, w2, Wpack2, Wpack1, ti, xi);
  k_xpose<<<DHW / 256, blk, 0, stream>>>(x, xb, xi);
  k_conv1m<<<128 * 128, blk, 0, stream>>>(xb, Wpack1, b1, hb);
  k_conv2<<<128 * 128, blk, 0, stream>>>(hb, Wpack2, wn);
  // adaptive ping-pong on interleaved fp32: xi -> ti -> xi -> out (planar)
  k_adapt2<0><<<DHW / 4 / 256, blk, 0, stream>>>(xi, wn, ti);
  k_adapt2<0><<<DHW / 4 / 256, blk, 0, stream>>>(ti, wn, xi);
  k_adapt2<1><<<DHW / 4 / 256, blk, 0, stream>>>(xi, wn, out);
}